// Round 5
// baseline (72.411 us; speedup 1.0000x reference)
//
#include <hip/hip_runtime.h>
#include <math.h>

namespace fc {

typedef float vf2 __attribute__((ext_vector_type(2)));
typedef float vf4 __attribute__((ext_vector_type(4)));

constexpr float ACT_SCALE = 10.0f;
constexpr float U_HOVER   = 0.515025f;          // -MASS*-9.81/10/1/4
constexpr float INV_MASS  = 1.0f / 2.1f;
constexpr float GM        = 2.1f * -9.81f;      // MASS * GVEC_z
constexpr float KM        = 0.025f;
constexpr float TAUC      = 0.175f * 0.70710678f; // MOTOR_DIST / sqrt(2)
constexpr float JXY       = 0.0023f;
constexpr float JZ        = 0.004f;
constexpr float INV_JXY   = 1.0f / 0.0023f;
constexpr float INV_JZ    = 1.0f / 0.004f;
constexpr float G3        = -9.81f;
constexpr float INV_L     = 2.0f;
constexpr float DT        = 0.05f;
constexpr float DT2       = 0.05f * 0.5f;
constexpr float DT6       = 0.05f / 6.0f;

__device__ __forceinline__ void quatrot(float s, float ax, float ay, float az,
                                        float vx, float vy, float vz,
                                        float& rx, float& ry, float& rz) {
  float tx = ay * vz - az * vy + s * vx;
  float ty = az * vx - ax * vz + s * vy;
  float tz = ax * vy - ay * vx + s * vz;
  rx = vx + 2.0f * (ay * tz - az * ty);
  ry = vy + 2.0f * (az * tx - ax * tz);
  rz = vz + 2.0f * (ax * ty - ay * tx);
}

__device__ __forceinline__ void dyn(const float* xt,
                                    float Fz, float taux, float tauy, float tauz,
                                    float* dx) {
  float mx = xt[3], my = xt[4], mz = xt[5];
  float th = xt[6];
  float vx = xt[7], vy = xt[8], vz = xt[9];
  float wx = xt[10], wy = xt[11], wz = xt[12];

  float n2  = mx * mx + my * my + mz * mz;
  float inv = __builtin_amdgcn_rcpf(1.0f + n2);   // ~1e-7 rel err, 1 inst
  float s   = (1.0f - n2) * inv;
  float qx  = 2.0f * mx * inv, qy = 2.0f * my * inv, qz = 2.0f * mz * inv;

  float fx, fy, fzz;
  quatrot(s, -qx, -qy, -qz, 0.0f, 0.0f, GM, fx, fy, fzz);
  fzz += Fz;

  quatrot(s, qx, qy, qz, vx, vy, vz, dx[0], dx[1], dx[2]);

  float mw  = mx * wx + my * wy + mz * wz;
  float on2 = 1.0f - n2;
  dx[3] = 0.25f * (on2 * wx + 2.0f * (my * wz - mz * wy) + 2.0f * mx * mw);
  dx[4] = 0.25f * (on2 * wy + 2.0f * (mz * wx - mx * wz) + 2.0f * my * mw);
  dx[5] = 0.25f * (on2 * wz + 2.0f * (mx * wy - my * wx) + 2.0f * mz * mw);

  dx[6] = xt[13];

  float vdx = fx * INV_MASS - (wy * vz - wz * vy);
  float vdy = fy * INV_MASS - (wz * vx - wx * vz);
  float vdz = fzz * INV_MASS - (wx * vy - wy * vx);
  dx[7] = vdx; dx[8] = vdy; dx[9] = vdz;

  float Jwx = JXY * wx, Jwy = JXY * wy, Jwz = JZ * wz;
  dx[10] = (taux - (wy * Jwz - wz * Jwy)) * INV_JXY;
  dx[11] = (tauy - (wz * Jwx - wx * Jwz)) * INV_JXY;
  dx[12] = (tauz - (wx * Jwy - wy * Jwx)) * INV_JZ;

  float rx, ry, rz;
  quatrot(s, qx, qy, qz, vdx, vdy, vdz, rx, ry, rz);
  float st = __sinf(th), ct = __cosf(th);    // v_sin_f32/v_cos_f32
  dx[13] = (G3 * st + rx * ct) * INV_L;
}

__device__ __forceinline__ void rk4_row(const float* x0, vf4 uv, float* o) {
  float su0 = ACT_SCALE * (uv.x + U_HOVER);
  float su1 = ACT_SCALE * (uv.y + U_HOVER);
  float su2 = ACT_SCALE * (uv.z + U_HOVER);
  float su3 = ACT_SCALE * (uv.w + U_HOVER);

  float Fz   = ((su0 + su1) + su2) + su3;
  float tauz = KM * (((su0 - su1) + su2) - su3);
  float taux = ((TAUC * su0 + (-TAUC) * su1) + (-TAUC) * su2) + TAUC * su3;
  float tauy = (((-TAUC) * su0 + (-TAUC) * su1) + TAUC * su2) + TAUC * su3;

  float xt[14], kk[14], acc[14];
  dyn(x0, Fz, taux, tauy, tauz, kk);
  #pragma unroll
  for (int j = 0; j < 14; ++j) { acc[j] = kk[j]; xt[j] = x0[j] + DT2 * kk[j]; }
  dyn(xt, Fz, taux, tauy, tauz, kk);
  #pragma unroll
  for (int j = 0; j < 14; ++j) { acc[j] += 2.0f * kk[j]; xt[j] = x0[j] + DT2 * kk[j]; }
  dyn(xt, Fz, taux, tauy, tauz, kk);
  #pragma unroll
  for (int j = 0; j < 14; ++j) { acc[j] += 2.0f * kk[j]; xt[j] = x0[j] + DT * kk[j]; }
  dyn(xt, Fz, taux, tauy, tauz, kk);
  #pragma unroll
  for (int j = 0; j < 14; ++j) o[j] = x0[j] + DT6 * (acc[j] + kk[j]);
}

// No LDS, no barriers: 7x b64 loads/stores per row (56B rows are only 8B-aligned).
// Every byte of the 56B-stride span is consumed -> no HBM over-fetch; waves drift
// freely so loads of some waves overlap compute of others.
__global__ __launch_bounds__(256) void fc_rk4_kernel(const float* __restrict__ x,
                                                     const float* __restrict__ u,
                                                     float* __restrict__ out,
                                                     int n) {
  const long long row = (long long)blockIdx.x * 256 + threadIdx.x;
  if (row >= n) return;

  float x0[14];
  const vf2* g2 = (const vf2*)(x + row * 14);
  #pragma unroll
  for (int j = 0; j < 7; ++j) {
    vf2 v = g2[j];
    x0[2 * j] = v.x; x0[2 * j + 1] = v.y;
  }
  vf4 uv = *(const vf4*)(u + row * 4);

  float o[14];
  rk4_row(x0, uv, o);

  vf2* o2 = (vf2*)(out + row * 14);
  #pragma unroll
  for (int j = 0; j < 7; ++j) {
    vf2 v; v.x = o[2 * j]; v.y = o[2 * j + 1];
    __builtin_nontemporal_store(v, o2 + j);
  }
}

}  // namespace fc

extern "C" void kernel_launch(void* const* d_in, const int* in_sizes, int n_in,
                              void* d_out, int out_size, void* d_ws, size_t ws_size,
                              hipStream_t stream) {
  const float* x = (const float*)d_in[0];
  const float* u = (const float*)d_in[1];
  float* out = (float*)d_out;
  const int n = in_sizes[0] / 14;
  const int grid = (n + 255) / 256;
  hipLaunchKernelGGL(fc::fc_rk4_kernel, dim3(grid), dim3(256), 0, stream,
                     x, u, out, n);
}

// Round 6
// 48.976 us; speedup vs baseline: 1.4785x; 1.4785x over previous
//
#include <hip/hip_runtime.h>
#include <math.h>

namespace fc {

typedef float vf2 __attribute__((ext_vector_type(2)));
typedef float vf4 __attribute__((ext_vector_type(4)));

__device__ __forceinline__ vf2 sp(float c) { return vf2{c, c}; }

constexpr float ACT_SCALE = 10.0f;
constexpr float U_HOVER   = 0.515025f;          // -MASS*-9.81/10/1/4
constexpr float INV_MASS  = 1.0f / 2.1f;
constexpr float KM        = 0.025f;
constexpr float TAUC      = 0.175f * 0.70710678f; // MOTOR_DIST / sqrt(2)
constexpr float JXY       = 0.0023f;
constexpr float JZ        = 0.004f;
constexpr float INV_JXY   = 1.0f / 0.0023f;
constexpr float INV_JZ    = 1.0f / 0.004f;
constexpr float G3        = -9.81f;
constexpr float INV_L     = 2.0f;
constexpr float DT        = 0.05f;
constexpr float DT2       = 0.05f * 0.5f;
constexpr float DT6       = 0.05f / 6.0f;

// Packed (2 rows/lane) dynamics. FzM = Fz/MASS precomputed (stage-invariant).
__device__ __forceinline__ void dyn2(const vf2* xt, vf2 FzM,
                                     vf2 taux, vf2 tauy, vf2 tauz, vf2* dx) {
  vf2 mx = xt[3], my = xt[4], mz = xt[5], th = xt[6];
  vf2 vx = xt[7], vy = xt[8], vz = xt[9];
  vf2 wx = xt[10], wy = xt[11], wz = xt[12];

  vf2 n2 = mx * mx + my * my + mz * mz;
  vf2 inv;
  inv.x = __builtin_amdgcn_rcpf(1.0f + n2.x);
  inv.y = __builtin_amdgcn_rcpf(1.0f + n2.y);
  vf2 s  = (sp(1.0f) - n2) * inv;
  vf2 qx = sp(2.0f) * mx * inv;
  vf2 qy = sp(2.0f) * my * inv;
  vf2 qz = sp(2.0f) * mz * inv;

  // gravity rotation quatrot(-q, (0,0,g)) hand-specialized (exact: dropped
  // terms are *0.0); g applied directly (MASS*g/MASS folded).
  vf2 gtx = qy * sp(-G3);                      // ay*vz with ay=-qy
  vf2 gty = qx * sp(G3);                       // -ax*vz with ax=-qx
  vf2 gtz = s * sp(G3);
  vf2 gx = sp(-2.0f) * (qy * gtz - qz * gty);
  vf2 gy = sp(-2.0f) * (qz * gtx - qx * gtz);
  vf2 gz = sp(G3) + sp(-2.0f) * (qx * gty - qy * gtx);

  // pdot = quatrot(q, v)
  vf2 tx = qy * vz - qz * vy + s * vx;
  vf2 ty = qz * vx - qx * vz + s * vy;
  vf2 tz = qx * vy - qy * vx + s * vz;
  dx[0] = vx + sp(2.0f) * (qy * tz - qz * ty);
  dx[1] = vy + sp(2.0f) * (qz * tx - qx * tz);
  dx[2] = vz + sp(2.0f) * (qx * ty - qy * tx);

  // mdot
  vf2 mw  = mx * wx + my * wy + mz * wz;
  vf2 on2 = sp(1.0f) - n2;
  dx[3] = sp(0.25f) * (on2 * wx + sp(2.0f) * (my * wz - mz * wy) + sp(2.0f) * mx * mw);
  dx[4] = sp(0.25f) * (on2 * wy + sp(2.0f) * (mz * wx - mx * wz) + sp(2.0f) * my * mw);
  dx[5] = sp(0.25f) * (on2 * wz + sp(2.0f) * (mx * wy - my * wx) + sp(2.0f) * mz * mw);

  dx[6] = xt[13];

  // vdot = (0,0,Fz/M) + g' - w x v
  vf2 vdx = gx - (wy * vz - wz * vy);
  vf2 vdy = gy - (wz * vx - wx * vz);
  vf2 vdz = FzM + gz - (wx * vy - wy * vx);
  dx[7] = vdx; dx[8] = vdy; dx[9] = vdz;

  // wdot
  vf2 Jwx = sp(JXY) * wx, Jwy = sp(JXY) * wy, Jwz = sp(JZ) * wz;
  dx[10] = (taux - (wy * Jwz - wz * Jwy)) * sp(INV_JXY);
  dx[11] = (tauy - (wz * Jwx - wx * Jwz)) * sp(INV_JXY);
  dx[12] = (tauz - (wx * Jwy - wy * Jwx)) * sp(INV_JZ);

  // x_ddot = quatrot(q, vdot).x only (ty,tz terms needed)
  vf2 t2y = qz * vdx - qx * vdz + s * vdy;
  vf2 t2z = qx * vdy - qy * vdx + s * vdz;
  vf2 rx  = vdx + sp(2.0f) * (qy * t2z - qz * t2y);
  vf2 st, ct;
  st.x = __sinf(th.x); st.y = __sinf(th.y);
  ct.x = __cosf(th.x); ct.y = __cosf(th.y);
  dx[13] = (sp(G3) * st + rx * ct) * sp(INV_L);
}

// Full RK4 for two rows; writes result row-wise to wA/wB (LDS), no o[] array.
__device__ __forceinline__ void rk4_rows(const vf2* x0, vf4 uA, vf4 uB,
                                         float* wA, float* wB) {
  vf2 su0 = sp(ACT_SCALE) * (vf2{uA.x, uB.x} + sp(U_HOVER));
  vf2 su1 = sp(ACT_SCALE) * (vf2{uA.y, uB.y} + sp(U_HOVER));
  vf2 su2 = sp(ACT_SCALE) * (vf2{uA.z, uB.z} + sp(U_HOVER));
  vf2 su3 = sp(ACT_SCALE) * (vf2{uA.w, uB.w} + sp(U_HOVER));

  vf2 Fz   = ((su0 + su1) + su2) + su3;
  vf2 FzM  = Fz * sp(INV_MASS);
  vf2 tauz = sp(KM) * (((su0 - su1) + su2) - su3);
  vf2 taux = ((sp(TAUC) * su0 + sp(-TAUC) * su1) + sp(-TAUC) * su2) + sp(TAUC) * su3;
  vf2 tauy = ((sp(-TAUC) * su0 + sp(-TAUC) * su1) + sp(TAUC) * su2) + sp(TAUC) * su3;

  vf2 xt[14], kk[14], acc[14];
  dyn2(x0, FzM, taux, tauy, tauz, kk);
  #pragma unroll
  for (int j = 0; j < 14; ++j) { acc[j] = kk[j]; xt[j] = x0[j] + sp(DT2) * kk[j]; }
  dyn2(xt, FzM, taux, tauy, tauz, kk);
  #pragma unroll
  for (int j = 0; j < 14; ++j) { acc[j] += sp(2.0f) * kk[j]; xt[j] = x0[j] + sp(DT2) * kk[j]; }
  dyn2(xt, FzM, taux, tauy, tauz, kk);
  #pragma unroll
  for (int j = 0; j < 14; ++j) { acc[j] += sp(2.0f) * kk[j]; xt[j] = x0[j] + sp(DT) * kk[j]; }
  dyn2(xt, FzM, taux, tauy, tauz, kk);
  #pragma unroll
  for (int j = 0; j < 14; ++j) {
    vf2 r = x0[j] + sp(DT6) * (acc[j] + kk[j]);
    wA[j] = r.x;
    wB[j] = r.y;
  }
}

// 512-row tile staged in LDS (coalesced vf4), 2 rows per thread packed into
// <2 x float> so the whole dynamics runs on v_pk_*_f32.
__global__ __launch_bounds__(256) void fc_rk4_kernel(const float* __restrict__ x,
                                                     const float* __restrict__ u,
                                                     float* __restrict__ out,
                                                     int n) {
  __shared__ float xs[512 * 14];  // 28672 B, linear copy of global layout
  const int t = threadIdx.x;
  const long long base = (long long)blockIdx.x * 512;

  if (base + 512 <= (long long)n) {
    const vf4* xg4 = (const vf4*)(x + base * 14);
    vf4* xs4 = (vf4*)xs;
    #pragma unroll
    for (int k = 0; k < 7; ++k)
      xs4[t + k * 256] = __builtin_nontemporal_load(xg4 + t + k * 256);
    __syncthreads();

    // rows rA = t, rB = t + 256 (each row touched by exactly one thread)
    vf2 x0[14];
    const float* rA = xs + t * 14;
    const float* rB = xs + (t + 256) * 14;
    #pragma unroll
    for (int j = 0; j < 14; ++j) x0[j] = vf2{rA[j], rB[j]};

    vf4 uA = *(const vf4*)(u + (base + t) * 4);
    vf4 uB = *(const vf4*)(u + (base + 256 + t) * 4);

    // write back into own rows — no cross-thread hazard, no barrier needed
    rk4_rows(x0, uA, uB, xs + t * 14, xs + (t + 256) * 14);
    __syncthreads();

    vf4* og4 = (vf4*)(out + base * 14);
    #pragma unroll
    for (int k = 0; k < 7; ++k)
      __builtin_nontemporal_store(xs4[t + k * 256], og4 + t + k * 256);
  } else {
    // tail (not hit at B=2M): per-row scalar path, row duplicated into both lanes
    #pragma unroll
    for (int k = 0; k < 2; ++k) {
      long long r = base + t + k * 256;
      if (r < n) {
        vf2 x0[14];
        #pragma unroll
        for (int j = 0; j < 14; ++j) { float v = x[r * 14 + j]; x0[j] = vf2{v, v}; }
        vf4 uv = *(const vf4*)(u + r * 4);
        float oA[14], oB[14];
        rk4_rows(x0, uv, uv, oA, oB);
        #pragma unroll
        for (int j = 0; j < 14; ++j) out[r * 14 + j] = oA[j];
      }
    }
  }
}

}  // namespace fc

extern "C" void kernel_launch(void* const* d_in, const int* in_sizes, int n_in,
                              void* d_out, int out_size, void* d_ws, size_t ws_size,
                              hipStream_t stream) {
  const float* x = (const float*)d_in[0];
  const float* u = (const float*)d_in[1];
  float* out = (float*)d_out;
  const int n = in_sizes[0] / 14;
  const int grid = (n + 511) / 512;
  hipLaunchKernelGGL(fc::fc_rk4_kernel, dim3(grid), dim3(256), 0, stream,
                     x, u, out, n);
}